// Round 1
// baseline (4332.423 us; speedup 1.0000x reference)
//
#include <hip/hip_runtime.h>

// NAS-cell RNN, persistent-kernel design:
//   512 rows x 256 units x 256 steps.
//   Grid: 256 WGs x 256 thr. WG = (rowblock rb of 32 rows) x (unit group w of 16 units).
//   rec_kernel held in REGISTERS as f16 hi/lo MFMA B-fragments (Markidis 3-product split,
//   K_eff = 768), h exchanged per step through d_ws with per-rowblock release/acquire counters.

#define NRB     16
#define RB_ROWS 32
#define WU      16
#define KST     24                         // 768 / 32
#define SLOT_ELEMS (NRB*2*RB_ROWS*256)     // f16 elements per h slot (512 KB)
#define CNT_STRIDE 32                      // uints -> 128B per rowblock counter

typedef _Float16 f16;
typedef f16  f16x8 __attribute__((ext_vector_type(8)));
typedef float f32x4 __attribute__((ext_vector_type(4)));

__device__ __forceinline__ float sigm_(float xx) {
  float e = __expf(-xx);
  return __builtin_amdgcn_rcpf(1.0f + e);
}
__device__ __forceinline__ float tanh_(float xx) {
  float ax = __builtin_fabsf(xx);
  float e  = __expf(-2.0f * ax);
  float r  = (1.0f - e) * __builtin_amdgcn_rcpf(1.0f + e);
  return __builtin_copysignf(r, xx);
}

__global__ __launch_bounds__(256, 1)
void nas_cell_rnn(const float* __restrict__ x,
                  const float* __restrict__ kern,
                  const float* __restrict__ rec,
                  float* __restrict__ out,
                  unsigned int* __restrict__ cnt,
                  f16* __restrict__ hbuf)
{
  const int tid  = threadIdx.x;
  const int lane = tid & 63;
  const int ww   = tid >> 6;        // wave 0..3 -> column quadrant
  const int wg   = blockIdx.x;
  const int rb   = wg >> 4;         // rowblock 0..15
  const int w    = wg & 15;         // unit group 0..15

  __shared__ float m_lds[RB_ROWS][132];   // padded pitch vs bank conflicts

  const int l15 = lane & 15;
  const int lg4 = lane >> 4;

  // ---- one-time: gather rec slice into register B-fragments (hi plane s<16, lo s>=16) ----
  // GEMM k-order: s<8: A=hi,B=hi ; 8<=s<16: A=lo,B=hi ; s>=16: A=hi,B=lo
  f16x8 bfr[2][KST];
#pragma unroll
  for (int ci = 0; ci < 2; ++ci) {
    const int colidx = 32*ww + 16*ci + l15;     // 0..127
    const int gate   = colidx >> 4;
    const int ucol   = colidx & 15;
    const int gcol   = gate*256 + w*WU + ucol;  // column in rec [256][2048]
#pragma unroll
    for (int s = 0; s < KST; ++s) {
      const int sb = (s < 8) ? s : ((s < 16) ? (s-8) : (s-16));
      const int ub = 32*sb;
      f16x8 v;
#pragma unroll
      for (int e = 0; e < 8; ++e) {
        const int k = ub + 8*lg4 + e;           // B-frag: k = 8*(lane>>4)+e, col = lane&15
        const float r = rec[k*2048 + gcol];
        const f16 hi = (f16)r;
        v[e] = (s >= 16) ? (f16)(r - (float)hi) : hi;
      }
      bfr[ci][s] = v;
    }
  }

  // per-thread cell mapping: cells (b0, ul) and (b0+16, ul)
  const int ul = tid & 15;
  const int b0 = tid >> 4;
  float kv[8];
#pragma unroll
  for (int g = 0; g < 8; ++g) kv[g] = kern[g*256 + w*WU + ul];

  float cst0 = 0.0f, cst1 = 0.0f;   // cell state c, register-resident

  const int arow = l15*256 + 8*lg4; // A-frag per-lane element offset within a plane
  unsigned int* const pcnt = cnt + rb*CNT_STRIDE;

  for (int t = 0; t < 256; ++t) {
    const float xv0 = x[(rb*RB_ROWS + b0)*256 + t];
    const float xv1 = x[(rb*RB_ROWS + b0 + 16)*256 + t];

    if (t > 0) {
      // ---- wait for h_t (all 16 unit-group WGs of this rowblock produced it) ----
      const unsigned int target = 16u * (unsigned int)t;
      int spins = 0;
      while (__hip_atomic_load(pcnt, __ATOMIC_RELAXED, __HIP_MEMORY_SCOPE_AGENT) < target) {
        if (++spins > 20000000) break;   // bail on bug instead of hanging the harness
      }
      (void)__hip_atomic_load(pcnt, __ATOMIC_ACQUIRE, __HIP_MEMORY_SCOPE_AGENT);

      const f16* const hsl = hbuf + (size_t)(t & 1) * SLOT_ELEMS;
      const f16* const p0  = hsl + (size_t)(rb*2 + 0) * RB_ROWS * 256;  // hi plane
      const f16* const p1  = hsl + (size_t)(rb*2 + 1) * RB_ROWS * 256;  // lo plane

      f32x4 acc00 = {0,0,0,0}, acc01 = {0,0,0,0}, acc10 = {0,0,0,0}, acc11 = {0,0,0,0};
#pragma unroll
      for (int s = 0; s < KST; ++s) {
        const int sb = (s < 8) ? s : ((s < 16) ? (s-8) : (s-16));
        const int ub = 32*sb;
        const f16* ap = (s >= 8 && s < 16) ? p1 : p0;
        const f16x8 a0 = *(const f16x8*)(ap + arow + ub);            // rows 0..15
        const f16x8 a1 = *(const f16x8*)(ap + arow + ub + 16*256);   // rows 16..31
        acc00 = __builtin_amdgcn_mfma_f32_16x16x32_f16(a0, bfr[0][s], acc00, 0, 0, 0);
        acc10 = __builtin_amdgcn_mfma_f32_16x16x32_f16(a1, bfr[0][s], acc10, 0, 0, 0);
        acc01 = __builtin_amdgcn_mfma_f32_16x16x32_f16(a0, bfr[1][s], acc01, 0, 0, 0);
        acc11 = __builtin_amdgcn_mfma_f32_16x16x32_f16(a1, bfr[1][s], acc11, 0, 0, 0);
      }
      // C layout (verified): col = lane&15, row = (lane>>4)*4 + j
      const int mrow = lg4*4;
      const int mc0  = 32*ww + l15;
#pragma unroll
      for (int j = 0; j < 4; ++j) {
        m_lds[mrow + j][mc0]           = acc00[j];
        m_lds[mrow + j][mc0 + 16]      = acc01[j];
        m_lds[16 + mrow + j][mc0]      = acc10[j];
        m_lds[16 + mrow + j][mc0 + 16] = acc11[j];
      }
    }
    __syncthreads();

    // ---- elementwise NAS cell: 2 cells per thread ----
#pragma unroll
    for (int cell = 0; cell < 2; ++cell) {
      const int   b  = b0 + 16*cell;
      const float xv = cell ? xv1 : xv0;
      const float cc = cell ? cst1 : cst0;
      float mg[8];
#pragma unroll
      for (int g = 0; g < 8; ++g)
        mg[g] = (t == 0) ? 0.0f : m_lds[b][g*WU + ul];

      const float i0 = xv*kv[0], i1 = xv*kv[1], i2 = xv*kv[2], i3 = xv*kv[3];
      const float i4 = xv*kv[4], i5 = xv*kv[5], i6 = xv*kv[6], i7 = xv*kv[7];

      const float l1_0 = sigm_(i0 + mg[0]);
      const float l1_1 = fmaxf(i1 + mg[1], 0.0f);
      const float l1_2 = sigm_(i2 + mg[2]);
      const float l1_3 = fmaxf(i3 * mg[3], 0.0f);
      const float l1_4 = tanh_(i4 + mg[4]);
      const float l1_5 = sigm_(i5 + mg[5]);
      const float l1_6 = tanh_(i6 + mg[6]);
      const float l1_7 = sigm_(i7 + mg[7]);

      float       l2_0 = tanh_(l1_0 * l1_1);
      const float l2_1 = tanh_(l1_2 + l1_3);
      const float l2_2 = tanh_(l1_4 * l1_5);
      const float l2_3 = sigm_(l1_6 + l1_7);

      l2_0 = tanh_(l2_0 + cc);
      const float nc = l2_0 * l2_1;
      const float l3 = tanh_(l2_2 + l2_3);
      const float nh = tanh_(nc * l3);
      if (cell) cst1 = nc; else cst0 = nc;

      if (t == 255) {
        out[(rb*RB_ROWS + b)*256 + w*WU + ul] = nh;
      } else {
        const f16 hh = (f16)nh;
        const f16 hl = (f16)(nh - (float)hh);
        f16* const dsl = hbuf + (size_t)((t + 1) & 1) * SLOT_ELEMS
                       + (size_t)(rb*2) * RB_ROWS * 256 + b*256 + w*WU + ul;
        dsl[0]           = hh;           // hi plane
        dsl[RB_ROWS*256] = hl;           // lo plane
      }
    }
    __syncthreads();   // drains vmcnt: all h-plane stores of all waves are in L2 here

    if (t < 255 && tid == 0)
      __hip_atomic_fetch_add(pcnt, 1u, __ATOMIC_RELEASE, __HIP_MEMORY_SCOPE_AGENT);
  }
}

extern "C" void kernel_launch(void* const* d_in, const int* in_sizes, int n_in,
                              void* d_out, int out_size, void* d_ws, size_t ws_size,
                              hipStream_t stream) {
  const float* x    = (const float*)d_in[0];   // [512, 256]
  const float* kern = (const float*)d_in[1];   // [1, 2048]
  const float* rec  = (const float*)d_in[2];   // [256, 2048]
  float* out = (float*)d_out;                  // [512, 256]

  unsigned int* cnt = (unsigned int*)d_ws;
  f16* hbuf = (f16*)((char*)d_ws + 4096);      // 2 slots x 512 KB

  hipMemsetAsync(d_ws, 0, 4096, stream);       // zero the rowblock counters every call
  hipLaunchKernelGGL(nas_cell_rnn, dim3(256), dim3(256), 0, stream,
                     x, kern, rec, out, cnt, hbuf);
}

// Round 2
// 994.048 us; speedup vs baseline: 4.3584x; 4.3584x over previous
//
#include <hip/hip_runtime.h>

// NAS-cell RNN, persistent-kernel, fence-free cross-WG handoff:
//   512 rows x 256 units x 256 steps.
//   Grid: 256 WGs x 256 thr. WG = (rowblock rb of 32 rows) x (unit group w of 16 units).
//   rec_kernel in registers as f16 hi/lo MFMA B-fragments (3-product split, K_eff=768).
//   h exchanged via d_ws using RELAXED agent atomics only (per-access sc1, no L2 inv/wb
//   fences -- the R1 killer). h packed {hi,lo} per value; consumer de-interleaves via
//   v_perm into padded LDS planes; MFMA A-frags read from LDS; x preloaded to LDS.

#define NRB     16
#define RB_ROWS 32
#define WU      16
#define KST     24                  // 768 / 32
#define LDSP    264                 // padded f16 pitch (256 + 8)
#define SLOT_BYTES (512*256*4)      // one h slot: 512 rows x 256 units x 4B = 512 KB
#define CNT_STRIDE 32

typedef _Float16 f16;
typedef f16  f16x8 __attribute__((ext_vector_type(8)));
typedef float f32x4 __attribute__((ext_vector_type(4)));
typedef unsigned int u32;
typedef unsigned long long u64;

__device__ __forceinline__ float sigm_(float xx) {
  float e = __expf(-xx);
  return __builtin_amdgcn_rcpf(1.0f + e);
}
__device__ __forceinline__ float tanh_(float xx) {
  float ax = __builtin_fabsf(xx);
  float e  = __expf(-2.0f * ax);
  float r  = (1.0f - e) * __builtin_amdgcn_rcpf(1.0f + e);
  return __builtin_copysignf(r, xx);
}

__global__ __launch_bounds__(256, 1)
void nas_cell_rnn(const float* __restrict__ x,
                  const float* __restrict__ kern,
                  const float* __restrict__ rec,
                  float* __restrict__ out,
                  u32* __restrict__ cnt,
                  char* __restrict__ hbuf)
{
  const int tid  = threadIdx.x;
  const int lane = tid & 63;
  const int ww   = tid >> 6;        // wave 0..3 -> column quadrant
  const int wg   = blockIdx.x;
  const int rb   = wg >> 4;         // rowblock 0..15
  const int w    = wg & 15;         // unit group 0..15

  __shared__ f16   h_lds[2][RB_ROWS][LDSP];   // 33792 B (hi, lo planes, padded)
  __shared__ float m_lds[RB_ROWS][132];       // 16896 B
  __shared__ float x_lds[RB_ROWS][256];       // 32768 B   total 83456 B -> 1 WG/CU

  const int l15 = lane & 15;
  const int lg4 = lane >> 4;

  // ---- one-time: rec slice into register B-fragments (hi s<16 plane use, lo s>=16) ----
  // k-order: s<8: A=hi,B=hi ; 8<=s<16: A=lo,B=hi ; s>=16: A=hi,B=lo
  f16x8 bfr[2][KST];
#pragma unroll
  for (int ci = 0; ci < 2; ++ci) {
    const int colidx = 32*ww + 16*ci + l15;     // 0..127
    const int gate   = colidx >> 4;
    const int ucol   = colidx & 15;
    const int gcol   = gate*256 + w*WU + ucol;  // column in rec [256][2048]
#pragma unroll
    for (int s = 0; s < KST; ++s) {
      const int sb = (s < 8) ? s : ((s < 16) ? (s-8) : (s-16));
      const int ub = 32*sb;
      f16x8 v;
#pragma unroll
      for (int e = 0; e < 8; ++e) {
        const int k = ub + 8*lg4 + e;           // B-frag: k = 8*(lane>>4)+e, col = lane&15
        const float r = rec[k*2048 + gcol];
        const f16 hi = (f16)r;
        v[e] = (s >= 16) ? (f16)(r - (float)hi) : hi;
      }
      bfr[ci][s] = v;
    }
  }

  // ---- one-time: x rows of this rowblock -> LDS ----
  {
    const float4* src = (const float4*)(x + (size_t)rb*RB_ROWS*256);
    float4* dst = (float4*)&x_lds[0][0];
#pragma unroll
    for (int i = 0; i < 8; ++i) dst[tid + 256*i] = src[tid + 256*i];
  }

  const int ul = tid & 15;          // unit within group
  const int b0 = tid >> 4;          // row 0..15 (also handles b0+16)
  float kv[8];
#pragma unroll
  for (int g = 0; g < 8; ++g) kv[g] = kern[g*256 + w*WU + ul];

  float cst0 = 0.0f, cst1 = 0.0f;

  u32*  const pcnt = cnt + rb*CNT_STRIDE;
  char* const hrb0 = hbuf + (size_t)rb * RB_ROWS * 256 * 4;   // this rowblock's 32KB block

  for (int t = 0; t < 256; ++t) {
    // ================= stage h_t -> LDS =================
    if (t > 0) {
      const u32 target = 16u * (u32)t;
      int spins = 0;
      while (__hip_atomic_load(pcnt, __ATOMIC_RELAXED, __HIP_MEMORY_SCOPE_AGENT) < target) {
        if (++spins > 20000000) break;   // bail on bug instead of hanging the harness
      }
      const char* srcb = hrb0 + (size_t)(t & 1) * SLOT_BYTES;
      // batch-issue all 16 u64 loads, then use (single waitcnt point)
      u64 q[16];
#pragma unroll
      for (int i = 0; i < 8; ++i) {
        const u64* p = (const u64*)(srcb + (tid + 256*i) * 16);
        q[2*i]   = __hip_atomic_load(p,     __ATOMIC_RELAXED, __HIP_MEMORY_SCOPE_AGENT);
        q[2*i+1] = __hip_atomic_load(p + 1, __ATOMIC_RELAXED, __HIP_MEMORY_SCOPE_AGENT);
      }
#pragma unroll
      for (int i = 0; i < 8; ++i) {
        const int c  = tid + 256*i;          // 16B chunk id: row = c>>6, units 4*(c&63)..+3
        const u32 d0 = (u32)q[2*i],   d1 = (u32)(q[2*i]   >> 32);
        const u32 d2 = (u32)q[2*i+1], d3 = (u32)(q[2*i+1] >> 32);
        const u32 h01 = __builtin_amdgcn_perm(d1, d0, 0x05040100u);  // hi f16 pair
        const u32 h23 = __builtin_amdgcn_perm(d3, d2, 0x05040100u);
        const u32 l01 = __builtin_amdgcn_perm(d1, d0, 0x07060302u);  // lo f16 pair
        const u32 l23 = __builtin_amdgcn_perm(d3, d2, 0x07060302u);
        const int r  = c >> 6;
        const int u0 = (c & 63) * 4;
        *(u64*)&h_lds[0][r][u0] = (u64)h01 | ((u64)h23 << 32);
        *(u64*)&h_lds[1][r][u0] = (u64)l01 | ((u64)l23 << 32);
      }
    }
    __syncthreads();

    // ================= m = h @ rec (MFMA from LDS) =================
    if (t > 0) {
      f32x4 acc00 = {0,0,0,0}, acc01 = {0,0,0,0}, acc10 = {0,0,0,0}, acc11 = {0,0,0,0};
#pragma unroll
      for (int s = 0; s < KST; ++s) {
        const int sb = (s < 8) ? s : ((s < 16) ? (s-8) : (s-16));
        const int ub = 32*sb;
        const int pl = (s >= 8 && s < 16) ? 1 : 0;
        const f16* ap = &h_lds[pl][0][0];
        const f16x8 a0 = *(const f16x8*)(ap + l15*LDSP        + ub + 8*lg4);
        const f16x8 a1 = *(const f16x8*)(ap + (l15+16)*LDSP   + ub + 8*lg4);
        acc00 = __builtin_amdgcn_mfma_f32_16x16x32_f16(a0, bfr[0][s], acc00, 0, 0, 0);
        acc10 = __builtin_amdgcn_mfma_f32_16x16x32_f16(a1, bfr[0][s], acc10, 0, 0, 0);
        acc01 = __builtin_amdgcn_mfma_f32_16x16x32_f16(a0, bfr[1][s], acc01, 0, 0, 0);
        acc11 = __builtin_amdgcn_mfma_f32_16x16x32_f16(a1, bfr[1][s], acc11, 0, 0, 0);
      }
      // C layout: col = lane&15, row = (lane>>4)*4 + j
      const int mrow = lg4*4;
      const int mc0  = 32*ww + l15;
#pragma unroll
      for (int j = 0; j < 4; ++j) {
        m_lds[mrow + j][mc0]           = acc00[j];
        m_lds[mrow + j][mc0 + 16]      = acc01[j];
        m_lds[16 + mrow + j][mc0]      = acc10[j];
        m_lds[16 + mrow + j][mc0 + 16] = acc11[j];
      }
    }
    __syncthreads();

    // ================= elementwise NAS cell: 2 cells/thread =================
#pragma unroll
    for (int cell = 0; cell < 2; ++cell) {
      const int   b  = b0 + 16*cell;
      const float xv = x_lds[b][t];
      const float cc = cell ? cst1 : cst0;
      float mg[8];
#pragma unroll
      for (int g = 0; g < 8; ++g)
        mg[g] = (t == 0) ? 0.0f : m_lds[b][g*WU + ul];

      const float i0 = xv*kv[0], i1 = xv*kv[1], i2 = xv*kv[2], i3 = xv*kv[3];
      const float i4 = xv*kv[4], i5 = xv*kv[5], i6 = xv*kv[6], i7 = xv*kv[7];

      const float l1_0 = sigm_(i0 + mg[0]);
      const float l1_1 = fmaxf(i1 + mg[1], 0.0f);
      const float l1_2 = sigm_(i2 + mg[2]);
      const float l1_3 = fmaxf(i3 * mg[3], 0.0f);
      const float l1_4 = tanh_(i4 + mg[4]);
      const float l1_5 = sigm_(i5 + mg[5]);
      const float l1_6 = tanh_(i6 + mg[6]);
      const float l1_7 = sigm_(i7 + mg[7]);

      float       l2_0 = tanh_(l1_0 * l1_1);
      const float l2_1 = tanh_(l1_2 + l1_3);
      const float l2_2 = tanh_(l1_4 * l1_5);
      const float l2_3 = sigm_(l1_6 + l1_7);

      l2_0 = tanh_(l2_0 + cc);
      const float nc = l2_0 * l2_1;
      const float l3 = tanh_(l2_2 + l2_3);
      const float nh = tanh_(nc * l3);
      if (cell) cst1 = nc; else cst0 = nc;

      if (t == 255) {
        out[(rb*RB_ROWS + b)*256 + w*WU + ul] = nh;
      } else {
        const f16 hh = (f16)nh;
        const f16 hl = (f16)(nh - (float)hh);
        const u32 val = (u32)__builtin_bit_cast(unsigned short, hh)
                      | ((u32)__builtin_bit_cast(unsigned short, hl) << 16);
        u32* dst = (u32*)(hrb0 + (size_t)((t + 1) & 1) * SLOT_BYTES) + (b*256 + w*WU + ul);
        __hip_atomic_store(dst, val, __ATOMIC_RELAXED, __HIP_MEMORY_SCOPE_AGENT);
      }
    }
    __syncthreads();   // compiler drains vmcnt before s_barrier -> all WG h stores done

    if (t < 255 && tid == 0)
      __hip_atomic_fetch_add(pcnt, 1u, __ATOMIC_RELAXED, __HIP_MEMORY_SCOPE_AGENT);
  }
}

extern "C" void kernel_launch(void* const* d_in, const int* in_sizes, int n_in,
                              void* d_out, int out_size, void* d_ws, size_t ws_size,
                              hipStream_t stream) {
  const float* x    = (const float*)d_in[0];   // [512, 256]
  const float* kern = (const float*)d_in[1];   // [1, 2048]
  const float* rec  = (const float*)d_in[2];   // [256, 2048]
  float* out = (float*)d_out;                  // [512, 256]

  u32* cnt  = (u32*)d_ws;
  char* hbuf = (char*)d_ws + 4096;             // 2 slots x 512 KB

  hipMemsetAsync(d_ws, 0, 4096, stream);       // zero rowblock counters every call
  hipLaunchKernelGGL(nas_cell_rnn, dim3(256), dim3(256), 0, stream,
                     x, kern, rec, out, cnt, (char*)hbuf);
}

// Round 5
// 900.989 us; speedup vs baseline: 4.8085x; 1.1033x over previous
//
#include <hip/hip_runtime.h>

// NAS-cell RNN, persistent kernel, XCD-local h-exchange (semantics-robust rebuild).
//   512 rows x 256 units x 256 steps. Grid 256 WGs x 256 thr.
//   WG = (rowblock rb = blockIdx&15, 32 rows) x (unit group w = blockIdx>>4, 16 units).
//   Rowblock's 16 WGs share blockIdx%8 -> one XCD under round-robin placement;
//   startup rendezvous verifies via HW_REG_XCC_ID, else falls back to the proven
//   R2 agent/sc1 (LLC) protocol.
//   FAST-PATH MECHANISMS (all L1-semantics-free):
//     poll  = global_atomic_add(+0, returning) -> executes at TCC/L2, never L1-stale
//     data  = plain dwordx4 loads; 3 slots => 64KB of other lines through the 32KB L1
//             between reuses of any address -> guaranteed refill from L2
//     flags = monotonic; per-launch base read after a global rendezvous (stale dirty
//             lines from a previous graph replay just become the base)
//   rec_kernel register-resident as f16 hi/lo B-frags (Markidis split, K_eff=768).

#define NRB     16
#define RB_ROWS 32
#define WU      16
#define KST     24                  // 768 / 32
#define LDSP    264                 // h_lds f16 pitch
#define NSLOT   3
#define SLOT_BYTES (512*256*4)      // one full h slot (512 KB)
#define RB_BYTES   (RB_ROWS*256*4)  // one rowblock slab (32 KB)
#define SPIN_STEP 500000
#define SPIN_RDV  5000000

typedef _Float16 f16;
typedef f16  f16x8 __attribute__((ext_vector_type(8)));
typedef float f32x4 __attribute__((ext_vector_type(4)));
typedef unsigned int u32;
typedef unsigned long long u64;

__device__ __forceinline__ float sigm_(float xx) {
  float e = __expf(-xx);
  return __builtin_amdgcn_rcpf(1.0f + e);
}
__device__ __forceinline__ float tanh_(float xx) {
  float ax = __builtin_fabsf(xx);
  float e  = __expf(-2.0f * ax);
  float r  = (1.0f - e) * __builtin_amdgcn_rcpf(1.0f + e);
  return __builtin_copysignf(r, xx);
}

// Atomic RMW executes at the TCC (XCD L2): authoritative read regardless of L1.
__device__ __forceinline__ u32 rmw_add0_l2(u32* p) {
  u32 r, z = 0;
  asm volatile("global_atomic_add %0, %1, %2, off sc0\n\ts_waitcnt vmcnt(0)"
               : "=v"(r) : "v"(p), "v"(z) : "memory");
  return r;
}
__device__ __forceinline__ void inc_l2(u32* p, u32 v) {
  asm volatile("global_atomic_add %0, %1, off" :: "v"(p), "v"(v) : "memory");
}

__global__ __launch_bounds__(256, 1)
void nas_cell_rnn(const float* __restrict__ x,
                  const float* __restrict__ kern,
                  const float* __restrict__ rec,
                  float* __restrict__ out,
                  u32* __restrict__ ws32,
                  char* __restrict__ hbuf)
{
  const int tid  = threadIdx.x;
  const int lane = tid & 63;
  const int ww   = tid >> 6;        // wave 0..3 -> column quadrant
  const int wg   = blockIdx.x;
  const int rb   = wg & 15;         // rowblock: members share blockIdx%8
  const int w    = wg >> 4;         // unit group 0..15

  __shared__ f16   h_lds[2][RB_ROWS][LDSP];   // 33792 B
  __shared__ float m_T[128][36];              // 18432 B (transposed m)
  __shared__ float x_lds[RB_ROWS][256];       // 32768 B
  __shared__ u32   fast_s;

  const int l15 = lane & 15;
  const int lg4 = lane >> 4;

  u32* const pcnt = ws32 + 288 + rb*32;       // 128B-strided per-rowblock flag

  // ---- rendezvous: publish XCC id, verify co-location, read flag base ----
  u32 xcc;
  asm("s_getreg_b32 %0, hwreg(HW_REG_XCC_ID)" : "=s"(xcc));
  u32 base = 0;
  if (tid == 0) {
    __hip_atomic_store(&ws32[wg], xcc, __ATOMIC_RELAXED, __HIP_MEMORY_SCOPE_AGENT);
    __hip_atomic_fetch_add(&ws32[256], 1u, __ATOMIC_RELEASE, __HIP_MEMORY_SCOPE_AGENT);
    int sp = 0;
    while (__hip_atomic_load(&ws32[256], __ATOMIC_RELAXED, __HIP_MEMORY_SCOPE_AGENT) < 256u)
      if (++sp > SPIN_RDV) break;
    u32 ok = 1;
    for (int w2 = 0; w2 < 16; ++w2) {
      u32 o = __hip_atomic_load(&ws32[w2*16 + rb], __ATOMIC_RELAXED, __HIP_MEMORY_SCOPE_AGENT);
      ok &= (o == xcc) ? 1u : 0u;
    }
    fast_s = ok;
    // base-readback: MUST precede any increment of this launch (phase-2 guards)
    base = ok ? rmw_add0_l2(pcnt)
              : __hip_atomic_load(pcnt, __ATOMIC_RELAXED, __HIP_MEMORY_SCOPE_AGENT);
    __hip_atomic_fetch_add(&ws32[260], 1u, __ATOMIC_RELEASE, __HIP_MEMORY_SCOPE_AGENT);
    sp = 0;
    while (__hip_atomic_load(&ws32[260], __ATOMIC_RELAXED, __HIP_MEMORY_SCOPE_AGENT) < 256u)
      if (++sp > SPIN_RDV) break;
  }
  __syncthreads();
  const bool fast = (fast_s != 0);

  // ---- one-time: rec slice -> register B-fragments ----
  // k-order: s<8: A=hi,B=hi ; 8<=s<16: A=lo,B=hi ; s>=16: A=hi,B=lo
  f16x8 bfr[2][KST];
#pragma unroll
  for (int ci = 0; ci < 2; ++ci) {
    const int colidx = 32*ww + 16*ci + l15;
    const int gate   = colidx >> 4;
    const int ucol   = colidx & 15;
    const int gcol   = gate*256 + w*WU + ucol;
#pragma unroll
    for (int s = 0; s < KST; ++s) {
      const int sb = (s < 8) ? s : ((s < 16) ? (s-8) : (s-16));
      const int ub = 32*sb;
      f16x8 v;
#pragma unroll
      for (int e = 0; e < 8; ++e) {
        const int k = ub + 8*lg4 + e;
        const float r = rec[k*2048 + gcol];
        const f16 hi = (f16)r;
        v[e] = (s >= 16) ? (f16)(r - (float)hi) : hi;
      }
      bfr[ci][s] = v;
    }
  }

  // ---- one-time: x rows -> LDS ----
  {
    const float4* src = (const float4*)(x + (size_t)rb*RB_ROWS*256);
    float4* dst = (float4*)&x_lds[0][0];
#pragma unroll
    for (int i = 0; i < 8; ++i) dst[tid + 256*i] = src[tid + 256*i];
  }

  const int ul = tid & 15;
  const int b0 = tid >> 4;
  float kv[8];
#pragma unroll
  for (int g = 0; g < 8; ++g) kv[g] = kern[g*256 + w*WU + ul];

  float cst0 = 0.0f, cst1 = 0.0f;
  int sr = 0, sw = 1;                          // read/write slot ids (t%3, (t+1)%3)

  for (int t = 0; t < 256; ++t) {
    // ================= wait + stage h_t -> LDS =================
    if (t > 0) {
      if (tid == 0) {
        const u32 tgt = base + 16u * (u32)t;
        int sp = 0;
        if (fast) {
          while (rmw_add0_l2(pcnt) < tgt)              // TCC-authoritative poll
            if (++sp > SPIN_STEP) break;
        } else {
          while (__hip_atomic_load(pcnt, __ATOMIC_RELAXED,
                                   __HIP_MEMORY_SCOPE_AGENT) < tgt)   // LLC poll
            if (++sp > SPIN_STEP) break;
        }
      }
      __syncthreads();    // release all waves; full compiler/memory ordering point

      const char* srcb = hbuf + (size_t)sr * SLOT_BYTES + (size_t)rb * RB_BYTES;
      u32 d[8][4];
      if (fast) {
        // plain dwordx4: L1 copies of these lines were evicted by 64KB of other
        // slot traffic since last reuse -> refill from XCD L2 (current values)
#pragma unroll
        for (int i = 0; i < 8; ++i) {
          const uint4 v = *(const uint4*)(srcb + (size_t)(tid + 256*i) * 16);
          d[i][0] = v.x; d[i][1] = v.y; d[i][2] = v.z; d[i][3] = v.w;
        }
      } else {
#pragma unroll
        for (int i = 0; i < 8; ++i) {
          const u64* p = (const u64*)(srcb + (size_t)(tid + 256*i) * 16);
          const u64 a = __hip_atomic_load(p,     __ATOMIC_RELAXED, __HIP_MEMORY_SCOPE_AGENT);
          const u64 b = __hip_atomic_load(p + 1, __ATOMIC_RELAXED, __HIP_MEMORY_SCOPE_AGENT);
          d[i][0] = (u32)a; d[i][1] = (u32)(a >> 32);
          d[i][2] = (u32)b; d[i][3] = (u32)(b >> 32);
        }
      }
#pragma unroll
      for (int i = 0; i < 8; ++i) {
        const int c = tid + 256*i;            // 16B chunk: row = c>>6, units 4*(c&63)..+3
        const u32 h01 = __builtin_amdgcn_perm(d[i][1], d[i][0], 0x05040100u);
        const u32 h23 = __builtin_amdgcn_perm(d[i][3], d[i][2], 0x05040100u);
        const u32 l01 = __builtin_amdgcn_perm(d[i][1], d[i][0], 0x07060302u);
        const u32 l23 = __builtin_amdgcn_perm(d[i][3], d[i][2], 0x07060302u);
        const int r  = c >> 6;
        const int u0 = (c & 63) * 4;
        *(u64*)&h_lds[0][r][u0] = (u64)h01 | ((u64)h23 << 32);
        *(u64*)&h_lds[1][r][u0] = (u64)l01 | ((u64)l23 << 32);
      }
    }
    __syncthreads();

    // ================= m = h @ rec (MFMA from LDS) =================
    if (t > 0) {
      f32x4 acc00 = {0,0,0,0}, acc01 = {0,0,0,0}, acc10 = {0,0,0,0}, acc11 = {0,0,0,0};
#pragma unroll
      for (int s = 0; s < KST; ++s) {
        const int sb = (s < 8) ? s : ((s < 16) ? (s-8) : (s-16));
        const int ub = 32*sb;
        const int pl = (s >= 8 && s < 16) ? 1 : 0;
        const f16* ap = &h_lds[pl][0][0];
        const f16x8 a0 = *(const f16x8*)(ap + l15*LDSP      + ub + 8*lg4);
        const f16x8 a1 = *(const f16x8*)(ap + (l15+16)*LDSP + ub + 8*lg4);
        acc00 = __builtin_amdgcn_mfma_f32_16x16x32_f16(a0, bfr[0][s], acc00, 0, 0, 0);
        acc10 = __builtin_amdgcn_mfma_f32_16x16x32_f16(a1, bfr[0][s], acc10, 0, 0, 0);
        acc01 = __builtin_amdgcn_mfma_f32_16x16x32_f16(a0, bfr[1][s], acc01, 0, 0, 0);
        acc11 = __builtin_amdgcn_mfma_f32_16x16x32_f16(a1, bfr[1][s], acc11, 0, 0, 0);
      }
      // C layout: col = lane&15, row = (lane>>4)*4 + j  ->  m_T[col][row], b128 writes
      const int mc0 = 32*ww + l15;
      const int r0  = 4*lg4;
      *(f32x4*)&m_T[mc0     ][r0]      = acc00;
      *(f32x4*)&m_T[mc0     ][16 + r0] = acc10;
      *(f32x4*)&m_T[mc0 + 16][r0]      = acc01;
      *(f32x4*)&m_T[mc0 + 16][16 + r0] = acc11;
    }
    __syncthreads();

    // ================= elementwise NAS cell: 2 cells/thread =================
#pragma unroll
    for (int cell = 0; cell < 2; ++cell) {
      const int   b  = b0 + 16*cell;
      const float xv = x_lds[b][t];
      const float cc = cell ? cst1 : cst0;
      float mg[8];
#pragma unroll
      for (int g = 0; g < 8; ++g)
        mg[g] = (t == 0) ? 0.0f : m_T[g*WU + ul][b];

      const float i0 = xv*kv[0], i1 = xv*kv[1], i2 = xv*kv[2], i3 = xv*kv[3];
      const float i4 = xv*kv[4], i5 = xv*kv[5], i6 = xv*kv[6], i7 = xv*kv[7];

      const float l1_0 = sigm_(i0 + mg[0]);
      const float l1_1 = fmaxf(i1 + mg[1], 0.0f);
      const float l1_2 = sigm_(i2 + mg[2]);
      const float l1_3 = fmaxf(i3 * mg[3], 0.0f);
      const float l1_4 = tanh_(i4 + mg[4]);
      const float l1_5 = sigm_(i5 + mg[5]);
      const float l1_6 = tanh_(i6 + mg[6]);
      const float l1_7 = sigm_(i7 + mg[7]);

      float       l2_0 = tanh_(l1_0 * l1_1);
      const float l2_1 = tanh_(l1_2 + l1_3);
      const float l2_2 = tanh_(l1_4 * l1_5);
      const float l2_3 = sigm_(l1_6 + l1_7);

      l2_0 = tanh_(l2_0 + cc);
      const float nc = l2_0 * l2_1;
      const float l3 = tanh_(l2_2 + l2_3);
      const float nh = tanh_(nc * l3);
      if (cell) cst1 = nc; else cst0 = nc;

      if (t == 255) {
        out[(rb*RB_ROWS + b)*256 + w*WU + ul] = nh;
      } else {
        const f16 hh = (f16)nh;
        const f16 hl = (f16)(nh - (float)hh);
        const u32 val = (u32)__builtin_bit_cast(unsigned short, hh)
                      | ((u32)__builtin_bit_cast(unsigned short, hl) << 16);
        u32* dst = (u32*)(hbuf + (size_t)sw * SLOT_BYTES + (size_t)rb * RB_BYTES)
                 + (b*256 + w*WU + ul);
        if (fast) *dst = val;   // write-through to shared XCD L2
        else __hip_atomic_store(dst, val, __ATOMIC_RELAXED, __HIP_MEMORY_SCOPE_AGENT);
      }
    }
    __syncthreads();   // drains vmcnt: all h stores of this WG complete before flag

    if (t < 255 && tid == 0) {
      if (fast) inc_l2(pcnt, 1u);                     // RMW at local TCC
      else __hip_atomic_fetch_add(pcnt, 1u, __ATOMIC_RELAXED, __HIP_MEMORY_SCOPE_AGENT);
    }
    sr = sw; sw = (sw == NSLOT-1) ? 0 : sw + 1;
  }
}

extern "C" void kernel_launch(void* const* d_in, const int* in_sizes, int n_in,
                              void* d_out, int out_size, void* d_ws, size_t ws_size,
                              hipStream_t stream) {
  (void)in_sizes; (void)n_in; (void)out_size; (void)ws_size;
  const float* x    = (const float*)d_in[0];   // [512, 256]
  const float* kern = (const float*)d_in[1];   // [1, 2048]
  const float* rec  = (const float*)d_in[2];   // [256, 2048]
  float* out = (float*)d_out;                  // [512, 256]

  u32*  ws32 = (u32*)d_ws;   // [0..255] xcc ids, [256] ph1, [260] ph2, 288+rb*32 flags
  char* hbuf = (char*)d_ws + 4096;             // 3 slots x 512 KB

  hipMemsetAsync(d_ws, 0, 4096, stream);
  hipLaunchKernelGGL(nas_cell_rnn, dim3(256), dim3(256), 0, stream,
                     x, kern, rec, out, ws32, hbuf);
}

// Round 6
// 716.421 us; speedup vs baseline: 6.0473x; 1.2576x over previous
//
#include <hip/hip_runtime.h>

// NAS-cell RNN, persistent kernel, XCD-local h-exchange, f16-h + lean MFMA path.
//   512 rows x 256 units x 256 steps. Grid 256 WGs x 256 thr.
//   WG = (rowblock rb = blockIdx&15, 32 rows) x (unit group w = blockIdx>>4, 16 units).
//   h exchanged as PLAIN f16 (16KB/rowblock/step); rec stays hi/lo split in registers
//   (error budget: ~1e-4/step through contractive gates, threshold 9.77e-3).
//   Staging: producers store with XOR-swizzled addresses (idx ^= (row&7)<<3, T2/m173:
//   swizzle the global source, keep LDS linear); consumers DMA the slab with
//   global_load_lds(16B); MFMA A-reads apply the same XOR -> bandwidth-floor LDS reads.
//   A-frag reuse: each A chunk read once, 8 MFMAs (B-hi + B-lo accumulate same acc).
//   Exchange protocol unchanged from R5 (proven): TCC RMW poll + base-readback +
//   co-location rendezvous with agent/sc1 fallback.

#define NRB     16
#define RB_ROWS 32
#define WU      16
#define NSLOT   4
#define SLAB_BYTES (RB_ROWS*256*2)       // 16 KB per rowblock per slot
#define SLOT_BYTES (NRB*SLAB_BYTES)      // 256 KB per slot
#define SPIN_STEP 500000
#define SPIN_RDV  5000000

typedef _Float16 f16;
typedef f16  f16x8 __attribute__((ext_vector_type(8)));
typedef float f32x4 __attribute__((ext_vector_type(4)));
typedef unsigned int u32;
typedef unsigned long long u64;

__device__ __forceinline__ float sigm_(float xx) {
  float e = __expf(-xx);
  return __builtin_amdgcn_rcpf(1.0f + e);
}
__device__ __forceinline__ float tanh_(float xx) {
  float ax = __builtin_fabsf(xx);
  float e  = __expf(-2.0f * ax);
  float r  = (1.0f - e) * __builtin_amdgcn_rcpf(1.0f + e);
  return __builtin_copysignf(r, xx);
}

// Atomic RMW executes at the TCC (XCD L2): authoritative read regardless of L1.
__device__ __forceinline__ u32 rmw_add0_l2(u32* p) {
  u32 r, z = 0;
  asm volatile("global_atomic_add %0, %1, %2, off sc0\n\ts_waitcnt vmcnt(0)"
               : "=v"(r) : "v"(p), "v"(z) : "memory");
  return r;
}
__device__ __forceinline__ void inc_l2(u32* p, u32 v) {
  asm volatile("global_atomic_add %0, %1, off" :: "v"(p), "v"(v) : "memory");
}

// Direct global->LDS DMA, 16B per lane (lds dest = uniform base + lane*16).
__device__ __forceinline__ void gld_lds16(const void* g, void* l) {
  __builtin_amdgcn_global_load_lds(
      (const __attribute__((address_space(1))) unsigned int*)g,
      (__attribute__((address_space(3))) unsigned int*)l, 16, 0, 0);
}

__global__ __launch_bounds__(256, 1)
void nas_cell_rnn(const float* __restrict__ x,
                  const float* __restrict__ kern,
                  const float* __restrict__ rec,
                  float* __restrict__ out,
                  u32* __restrict__ ws32,
                  char* __restrict__ hbuf)
{
  const int tid  = threadIdx.x;
  const int lane = tid & 63;
  const int ww   = tid >> 6;        // wave 0..3 -> column quadrant
  const int wg   = blockIdx.x;
  const int rb   = wg & 15;         // rowblock: members share blockIdx%8 (one XCD)
  const int w    = wg >> 4;         // unit group 0..15

  __shared__ f16   h_lds[RB_ROWS][256];   // 16 KB, LINEAR (DMA target); content XOR-swz
  __shared__ float m_T[128][36];          // 18 KB (transposed m)
  __shared__ float x_lds[RB_ROWS][256];   // 32 KB
  __shared__ u32   fast_s;

  const int l15 = lane & 15;
  const int lg4 = lane >> 4;

  u32* const pcnt = ws32 + 288 + rb*32;   // 128B-strided per-rowblock flag

  // ---- rendezvous: publish XCC id, verify co-location, read flag base ----
  u32 xcc;
  asm("s_getreg_b32 %0, hwreg(HW_REG_XCC_ID)" : "=s"(xcc));
  u32 base = 0;
  if (tid == 0) {
    __hip_atomic_store(&ws32[wg], xcc, __ATOMIC_RELAXED, __HIP_MEMORY_SCOPE_AGENT);
    __hip_atomic_fetch_add(&ws32[256], 1u, __ATOMIC_RELEASE, __HIP_MEMORY_SCOPE_AGENT);
    int sp = 0;
    while (__hip_atomic_load(&ws32[256], __ATOMIC_RELAXED, __HIP_MEMORY_SCOPE_AGENT) < 256u)
      if (++sp > SPIN_RDV) break;
    u32 ok = 1;
    for (int w2 = 0; w2 < 16; ++w2) {
      u32 o = __hip_atomic_load(&ws32[w2*16 + rb], __ATOMIC_RELAXED, __HIP_MEMORY_SCOPE_AGENT);
      ok &= (o == xcc) ? 1u : 0u;
    }
    fast_s = ok;
    // base-readback MUST precede any increment of this launch (phase-2 guards)
    base = ok ? rmw_add0_l2(pcnt)
              : __hip_atomic_load(pcnt, __ATOMIC_RELAXED, __HIP_MEMORY_SCOPE_AGENT);
    __hip_atomic_fetch_add(&ws32[260], 1u, __ATOMIC_RELEASE, __HIP_MEMORY_SCOPE_AGENT);
    sp = 0;
    while (__hip_atomic_load(&ws32[260], __ATOMIC_RELAXED, __HIP_MEMORY_SCOPE_AGENT) < 256u)
      if (++sp > SPIN_RDV) break;
  }
  __syncthreads();
  const bool fast = (fast_s != 0);

  // ---- one-time: rec slice -> register B-fragments, hi (pl=0) and lo (pl=1) ----
  f16x8 bfr[2][2][8];                 // [ci][plane][chunk]
#pragma unroll
  for (int ci = 0; ci < 2; ++ci) {
    const int colidx = 32*ww + 16*ci + l15;     // 0..127
    const int gate   = colidx >> 4;
    const int ucol   = colidx & 15;
    const int gcol   = gate*256 + w*WU + ucol;  // column in rec [256][2048]
#pragma unroll
    for (int sb = 0; sb < 8; ++sb) {
      f16x8 vh, vl;
#pragma unroll
      for (int e = 0; e < 8; ++e) {
        const int k = 32*sb + 8*lg4 + e;        // B-frag: k = 8*(lane>>4)+e, col = lane&15
        const float r = rec[k*2048 + gcol];
        const f16 hi = (f16)r;
        vh[e] = hi;
        vl[e] = (f16)(r - (float)hi);
      }
      bfr[ci][0][sb] = vh;
      bfr[ci][1][sb] = vl;
    }
  }

  // ---- one-time: x rows -> LDS ----
  {
    const float4* src = (const float4*)(x + (size_t)rb*RB_ROWS*256);
    float4* dst = (float4*)&x_lds[0][0];
#pragma unroll
    for (int i = 0; i < 8; ++i) dst[tid + 256*i] = src[tid + 256*i];
  }

  const int ul = tid & 15;
  const int b0 = tid >> 4;
  float kv[8];
#pragma unroll
  for (int g = 0; g < 8; ++g) kv[g] = kern[g*256 + w*WU + ul];

  float cst0 = 0.0f, cst1 = 0.0f;
  int sr = 0, sw = 1;                // read/write slot ids

  char* const hrb = hbuf + (size_t)rb * SLAB_BYTES;   // rowblock slab within a slot

  for (int t = 0; t < 256; ++t) {
    // ================= wait + DMA h_t slab -> LDS =================
    if (t > 0) {
      if (tid == 0) {
        const u32 tgt = base + 16u * (u32)t;
        int sp = 0;
        if (fast) {
          while (rmw_add0_l2(pcnt) < tgt)              // TCC-authoritative poll
            if (++sp > SPIN_STEP) break;
        } else {
          while (__hip_atomic_load(pcnt, __ATOMIC_RELAXED,
                                   __HIP_MEMORY_SCOPE_AGENT) < tgt)   // LLC poll
            if (++sp > SPIN_STEP) break;
        }
      }
      __syncthreads();    // release all waves; ordering point

      const char* srcb = hrb + (size_t)sr * SLOT_BYTES;
      if (fast) {
        // 4 x 1KB DMA per wave: lds[base + lane*16] <- g[base + lane*16]
#pragma unroll
        for (int i = 0; i < 4; ++i) {
          const int off = ww*4096 + i*1024;
          gld_lds16(srcb + off + lane*16, (char*)&h_lds[0][0] + off);
        }
        asm volatile("s_waitcnt vmcnt(0)" ::: "memory");
      } else {
        // agent/sc1 path: 64B per thread via relaxed atomic u64 loads
        const u64* p = (const u64*)(srcb + (size_t)tid * 64);
        u64 v[8];
#pragma unroll
        for (int j = 0; j < 8; ++j)
          v[j] = __hip_atomic_load(p + j, __ATOMIC_RELAXED, __HIP_MEMORY_SCOPE_AGENT);
        u64* lp = (u64*)((char*)&h_lds[0][0] + (size_t)tid * 64);
#pragma unroll
        for (int j = 0; j < 8; ++j) lp[j] = v[j];
      }
    }
    __syncthreads();

    // ================= m = h @ rec (MFMA, A-frag reuse, XOR-swz reads) ============
    if (t > 0) {
      f32x4 acc00 = {0,0,0,0}, acc01 = {0,0,0,0}, acc10 = {0,0,0,0}, acc11 = {0,0,0,0};
      const f16* hb = &h_lds[0][0] + l15*256;
      const int axor = (l15 & 7) << 3;          // f16-unit XOR (bits 3..5) = byte<<4
#pragma unroll
      for (int sb = 0; sb < 8; ++sb) {
        const int col = (32*sb + 8*lg4) ^ axor;
        const f16x8 a0 = *(const f16x8*)(hb + col);            // rows 0..15
        const f16x8 a1 = *(const f16x8*)(hb + 16*256 + col);   // rows 16..31 (same xor)
        acc00 = __builtin_amdgcn_mfma_f32_16x16x32_f16(a0, bfr[0][0][sb], acc00, 0, 0, 0);
        acc10 = __builtin_amdgcn_mfma_f32_16x16x32_f16(a1, bfr[0][0][sb], acc10, 0, 0, 0);
        acc01 = __builtin_amdgcn_mfma_f32_16x16x32_f16(a0, bfr[1][0][sb], acc01, 0, 0, 0);
        acc11 = __builtin_amdgcn_mfma_f32_16x16x32_f16(a1, bfr[1][0][sb], acc11, 0, 0, 0);
        acc00 = __builtin_amdgcn_mfma_f32_16x16x32_f16(a0, bfr[0][1][sb], acc00, 0, 0, 0);
        acc10 = __builtin_amdgcn_mfma_f32_16x16x32_f16(a1, bfr[0][1][sb], acc10, 0, 0, 0);
        acc01 = __builtin_amdgcn_mfma_f32_16x16x32_f16(a0, bfr[1][1][sb], acc01, 0, 0, 0);
        acc11 = __builtin_amdgcn_mfma_f32_16x16x32_f16(a1, bfr[1][1][sb], acc11, 0, 0, 0);
      }
      // C layout: col = lane&15, row = (lane>>4)*4 + j  ->  m_T[col][row], b128 writes
      const int mc0 = 32*ww + l15;
      const int r0  = 4*lg4;
      *(f32x4*)&m_T[mc0     ][r0]      = acc00;
      *(f32x4*)&m_T[mc0     ][16 + r0] = acc10;
      *(f32x4*)&m_T[mc0 + 16][r0]      = acc01;
      *(f32x4*)&m_T[mc0 + 16][16 + r0] = acc11;
    }
    __syncthreads();

    // ================= elementwise NAS cell: 2 cells/thread =================
#pragma unroll
    for (int cell = 0; cell < 2; ++cell) {
      const int   b  = b0 + 16*cell;
      const float xv = x_lds[b][t];
      const float cc = cell ? cst1 : cst0;
      float mg[8];
#pragma unroll
      for (int g = 0; g < 8; ++g)
        mg[g] = (t == 0) ? 0.0f : m_T[g*WU + ul][b];

      const float i0 = xv*kv[0], i1 = xv*kv[1], i2 = xv*kv[2], i3 = xv*kv[3];
      const float i4 = xv*kv[4], i5 = xv*kv[5], i6 = xv*kv[6], i7 = xv*kv[7];

      const float l1_0 = sigm_(i0 + mg[0]);
      const float l1_1 = fmaxf(i1 + mg[1], 0.0f);
      const float l1_2 = sigm_(i2 + mg[2]);
      const float l1_3 = fmaxf(i3 * mg[3], 0.0f);
      const float l1_4 = tanh_(i4 + mg[4]);
      const float l1_5 = sigm_(i5 + mg[5]);
      const float l1_6 = tanh_(i6 + mg[6]);
      const float l1_7 = sigm_(i7 + mg[7]);

      float       l2_0 = tanh_(l1_0 * l1_1);
      const float l2_1 = tanh_(l1_2 + l1_3);
      const float l2_2 = tanh_(l1_4 * l1_5);
      const float l2_3 = sigm_(l1_6 + l1_7);

      l2_0 = tanh_(l2_0 + cc);
      const float nc = l2_0 * l2_1;
      const float l3 = tanh_(l2_2 + l2_3);
      const float nh = tanh_(nc * l3);
      if (cell) cst1 = nc; else cst0 = nc;

      if (t == 255) {
        out[(rb*RB_ROWS + b)*256 + w*WU + ul] = nh;
      } else {
        // XOR-swizzled store: consumer's linear DMA + swizzled read recovers layout
        const int idx = (b*256 + (w*WU + ul)) ^ ((b & 7) << 3);
        f16* dst = (f16*)(hrb + (size_t)sw * SLOT_BYTES) + idx;
        if (fast) {
          *dst = (f16)nh;             // plain store -> shared XCD L2
        } else {
          unsigned short us = __builtin_bit_cast(unsigned short, (f16)nh);
          __hip_atomic_store((unsigned short*)dst, us,
                             __ATOMIC_RELAXED, __HIP_MEMORY_SCOPE_AGENT);
        }
      }
    }
    __syncthreads();   // drains vmcnt: all h stores of this WG complete before flag

    if (t < 255 && tid == 0) {
      if (fast) inc_l2(pcnt, 1u);                     // RMW at local TCC
      else __hip_atomic_fetch_add(pcnt, 1u, __ATOMIC_RELAXED, __HIP_MEMORY_SCOPE_AGENT);
    }
    sr = sw; sw = (sw == NSLOT-1) ? 0 : sw + 1;
  }
}

extern "C" void kernel_launch(void* const* d_in, const int* in_sizes, int n_in,
                              void* d_out, int out_size, void* d_ws, size_t ws_size,
                              hipStream_t stream) {
  (void)in_sizes; (void)n_in; (void)out_size; (void)ws_size;
  const float* x    = (const float*)d_in[0];   // [512, 256]
  const float* kern = (const float*)d_in[1];   // [1, 2048]
  const float* rec  = (const float*)d_in[2];   // [256, 2048]
  float* out = (float*)d_out;                  // [512, 256]

  u32*  ws32 = (u32*)d_ws;   // [0..255] xcc ids, [256] ph1, [260] ph2, 288+rb*32 flags
  char* hbuf = (char*)d_ws + 4096;             // 4 slots x 256 KB

  hipMemsetAsync(d_ws, 0, 4096, stream);
  hipLaunchKernelGGL(nas_cell_rnn, dim3(256), dim3(256), 0, stream,
                     x, kern, rec, out, ws32, hbuf);
}